// Round 1
// baseline (2996.200 us; speedup 1.0000x reference)
//
#include <hip/hip_runtime.h>
#include <hip/hip_bf16.h>
#include <cmath>

// Problem constants
constexpr int Bc  = 2;
constexpr int Sc  = 2048;
constexpr int Dc  = 768;
constexpr int Hc  = 12;
constexpr int Ec  = 64;          // d_head
constexpr int BSc = Bc * Sc;     // 4096

// ---------------------------------------------------------------------------
// Kernel 1: QKV projection.  C[4096,64] = X[4096,768] @ W_h[768,64] + b_h
// q stored [H,B,S,E]; k,v stored TRANSPOSED [H,B,E,S] for coalesced attention.
// 64x64 output tile per block, 256 threads (16x16), 4x4 accum per thread.
// ---------------------------------------------------------------------------
__global__ __launch_bounds__(256, 2) void qkv_proj_kernel(
    const float* __restrict__ x,
    const float* __restrict__ Wq, const float* __restrict__ bq,
    const float* __restrict__ Wk, const float* __restrict__ bk,
    const float* __restrict__ Wv, const float* __restrict__ bv,
    float* __restrict__ q_out, float* __restrict__ kt_out, float* __restrict__ vt_out)
{
    __shared__ __align__(16) float Xs[64][68];  // transposed: Xs[k][row]
    __shared__ __align__(16) float Ws[64][68];  // Ws[k][col]
    __shared__ __align__(16) float Cs[64][68];  // [row][col] staging for transposed store

    const int stile = blockIdx.x;        // 0..63  (64 rows of B*S each)
    const int h     = blockIdx.y;        // 0..11
    const int proj  = blockIdx.z;        // 0=q 1=k 2=v
    const int tx = threadIdx.x;          // 0..15
    const int ty = threadIdx.y;          // 0..15
    const int t  = ty * 16 + tx;
    const int s0 = stile * 64;

    const float* W; const float* bias;
    if (proj == 0)      { W = Wq; bias = bq; }
    else if (proj == 1) { W = Wk; bias = bk; }
    else                { W = Wv; bias = bv; }

    const int lc = t & 63;   // 0..63
    const int lr = t >> 6;   // 0..3

    float acc[4][4];
    #pragma unroll
    for (int i = 0; i < 4; ++i)
        #pragma unroll
        for (int j = 0; j < 4; ++j) acc[i][j] = 0.f;

    for (int ktile = 0; ktile < Dc / 64; ++ktile) {
        #pragma unroll
        for (int rr = 0; rr < 16; ++rr) {
            const int r = lr + rr * 4;
            Xs[lc][r] = x[(size_t)(s0 + r) * Dc + ktile * 64 + lc];            // coalesced
            Ws[r][lc] = W[(size_t)(h * Dc + ktile * 64 + r) * Ec + lc];        // coalesced
        }
        __syncthreads();
        #pragma unroll
        for (int kk = 0; kk < 64; ++kk) {
            const float4 av  = *(const float4*)&Xs[kk][ty * 4];
            const float4 bv4 = *(const float4*)&Ws[kk][tx * 4];
            const float a_[4] = {av.x, av.y, av.z, av.w};
            const float b_[4] = {bv4.x, bv4.y, bv4.z, bv4.w};
            #pragma unroll
            for (int i = 0; i < 4; ++i)
                #pragma unroll
                for (int j = 0; j < 4; ++j)
                    acc[i][j] += a_[i] * b_[j];
        }
        __syncthreads();
    }

    if (proj == 0) {
        // q: direct store [H,B,S,E] (flat: (h*BS + s_global)*E + e), coalesced per 4
        #pragma unroll
        for (int i = 0; i < 4; ++i) {
            const int row = ty * 4 + i;
            const size_t off = ((size_t)h * BSc + s0 + row) * Ec + tx * 4;
            #pragma unroll
            for (int j = 0; j < 4; ++j)
                q_out[off + j] = acc[i][j] + bias[h * Ec + tx * 4 + j];
        }
    } else {
        // k/v: stage tile, then transposed coalesced store into [H,B,E,S]
        #pragma unroll
        for (int i = 0; i < 4; ++i)
            #pragma unroll
            for (int j = 0; j < 4; ++j)
                Cs[ty * 4 + i][tx * 4 + j] = acc[i][j] + bias[h * Ec + tx * 4 + j];
        __syncthreads();
        const int b   = s0 / Sc;
        const int sin = s0 % Sc;
        float* dst = (proj == 1) ? kt_out : vt_out;
        const size_t base = ((size_t)(h * Bc + b) * Ec) * Sc;
        #pragma unroll
        for (int it = 0; it < 16; ++it) {
            const int e = lr + it * 4;
            dst[base + (size_t)e * Sc + sin + lc] = Cs[lc][e];   // coalesced over lc
        }
    }
}

// ---------------------------------------------------------------------------
// Kernel 2: attention. One block (256 thr) per (query row i, b, h).
// Phase1: logits over all 2048 keys (coalesced K^T reads) + mask.
// Phase2: softmax (shuffle + LDS reduce). Phase3: o = sum p*v (V^T coalesced).
// ---------------------------------------------------------------------------
__global__ __launch_bounds__(256, 4) void attn_kernel(
    const float* __restrict__ q, const float* __restrict__ kt,
    const float* __restrict__ vt, const float* __restrict__ mask,
    float* __restrict__ obuf)
{
    __shared__ float qs[Ec];
    __shared__ float Ls[Sc];
    __shared__ float red[8];
    __shared__ float os[Ec];

    const int i = blockIdx.x;
    const int b = blockIdx.y;
    const int h = blockIdx.z;
    const int hb = h * Bc + b;
    const int t = threadIdx.x;
    const int lane = t & 63;
    const int wave = t >> 6;

    if (t < Ec) qs[t] = q[((size_t)h * BSc + (size_t)b * Sc + i) * Ec + t];
    __syncthreads();

    const float* kb   = kt + (size_t)hb * Ec * Sc;
    const float* vb   = vt + (size_t)hb * Ec * Sc;
    const float* mrow = mask + ((size_t)hb * Sc + i) * Sc;

    // Phase 1: logits
    for (int jt = 0; jt < Sc / 256; ++jt) {
        const int j = jt * 256 + t;
        float a = 0.f;
        #pragma unroll 16
        for (int e = 0; e < Ec; ++e)
            a += qs[e] * kb[(size_t)e * Sc + j];   // coalesced over j
        Ls[j] = a + mrow[j];
    }
    __syncthreads();

    // Phase 2: softmax
    float m = -1e30f;
    #pragma unroll
    for (int jt = 0; jt < 8; ++jt) m = fmaxf(m, Ls[jt * 256 + t]);
    #pragma unroll
    for (int off = 32; off > 0; off >>= 1) m = fmaxf(m, __shfl_down(m, off, 64));
    if (lane == 0) red[wave] = m;
    __syncthreads();
    const float mall = fmaxf(fmaxf(red[0], red[1]), fmaxf(red[2], red[3]));

    float ssum = 0.f;
    #pragma unroll
    for (int jt = 0; jt < 8; ++jt) {
        const int j = jt * 256 + t;
        const float p = __expf(Ls[j] - mall);
        Ls[j] = p;
        ssum += p;
    }
    #pragma unroll
    for (int off = 32; off > 0; off >>= 1) ssum += __shfl_down(ssum, off, 64);
    if (lane == 0) red[4 + wave] = ssum;
    __syncthreads();
    const float inv = 1.f / (red[4] + red[5] + red[6] + red[7]);

    // Phase 3: o[e] = sum_j p_j * v[j][e]  (wave w handles e = w*16..w*16+15)
    for (int ii = 0; ii < 16; ++ii) {
        const int e = wave * 16 + ii;
        const float* vrow = vb + (size_t)e * Sc;
        float a = 0.f;
        #pragma unroll 8
        for (int jc = 0; jc < Sc / 64; ++jc)
            a += Ls[jc * 64 + lane] * vrow[jc * 64 + lane];  // coalesced
        #pragma unroll
        for (int off = 32; off > 0; off >>= 1) a += __shfl_down(a, off, 64);
        if (lane == 0) os[e] = a * inv;
    }
    __syncthreads();
    // concat-heads layout [B,S,H,E]
    if (t < Ec) obuf[(((size_t)b * Sc + i) * Hc + h) * Ec + t] = os[t];
}

// ---------------------------------------------------------------------------
// Kernel 3: output projection. out[4096,768] = obuf[4096,768] @ Wo[768,768] + bo
// ---------------------------------------------------------------------------
__global__ __launch_bounds__(256, 2) void out_proj_kernel(
    const float* __restrict__ obuf, const float* __restrict__ Wo,
    const float* __restrict__ bo, float* __restrict__ out)
{
    __shared__ __align__(16) float Xs[64][68];  // transposed [k][row]
    __shared__ __align__(16) float Ws[64][68];  // [k][col]

    const int rt = blockIdx.x;   // 0..63
    const int ct = blockIdx.y;   // 0..11
    const int tx = threadIdx.x, ty = threadIdx.y;
    const int t  = ty * 16 + tx;
    const int lc = t & 63, lr = t >> 6;

    float acc[4][4];
    #pragma unroll
    for (int i = 0; i < 4; ++i)
        #pragma unroll
        for (int j = 0; j < 4; ++j) acc[i][j] = 0.f;

    for (int ktile = 0; ktile < Dc / 64; ++ktile) {
        #pragma unroll
        for (int rr = 0; rr < 16; ++rr) {
            const int r = lr + rr * 4;
            Xs[lc][r] = obuf[(size_t)(rt * 64 + r) * Dc + ktile * 64 + lc];
            Ws[r][lc] = Wo[(size_t)(ktile * 64 + r) * Dc + ct * 64 + lc];
        }
        __syncthreads();
        #pragma unroll
        for (int kk = 0; kk < 64; ++kk) {
            const float4 av  = *(const float4*)&Xs[kk][ty * 4];
            const float4 bv4 = *(const float4*)&Ws[kk][tx * 4];
            const float a_[4] = {av.x, av.y, av.z, av.w};
            const float b_[4] = {bv4.x, bv4.y, bv4.z, bv4.w};
            #pragma unroll
            for (int i = 0; i < 4; ++i)
                #pragma unroll
                for (int j = 0; j < 4; ++j)
                    acc[i][j] += a_[i] * b_[j];
        }
        __syncthreads();
    }

    #pragma unroll
    for (int i = 0; i < 4; ++i) {
        const int row = rt * 64 + ty * 4 + i;
        #pragma unroll
        for (int j = 0; j < 4; ++j) {
            const int col = ct * 64 + tx * 4 + j;
            out[(size_t)row * Dc + col] = acc[i][j] + bo[col];
        }
    }
}

// ---------------------------------------------------------------------------
extern "C" void kernel_launch(void* const* d_in, const int* in_sizes, int n_in,
                              void* d_out, int out_size, void* d_ws, size_t ws_size,
                              hipStream_t stream)
{
    const float* x    = (const float*)d_in[0];
    const float* mask = (const float*)d_in[1];
    const float* Wq   = (const float*)d_in[2];
    const float* bq   = (const float*)d_in[3];
    const float* Wk   = (const float*)d_in[4];
    const float* bk   = (const float*)d_in[5];
    const float* Wv   = (const float*)d_in[6];
    const float* bv   = (const float*)d_in[7];
    const float* Wo   = (const float*)d_in[8];
    const float* bo   = (const float*)d_in[9];
    float* out = (float*)d_out;

    // workspace layout (floats): q | k_t | v_t | obuf, each H*B*S*E = 3,145,728
    constexpr size_t NQ = (size_t)Hc * Bc * Sc * Ec;  // 3145728
    float* ws   = (float*)d_ws;
    float* q    = ws;
    float* k_t  = ws + NQ;
    float* v_t  = ws + 2 * NQ;
    float* obuf = ws + 3 * NQ;

    qkv_proj_kernel<<<dim3(BSc / 64, Hc, 3), dim3(16, 16), 0, stream>>>(
        x, Wq, bq, Wk, bk, Wv, bv, q, k_t, v_t);

    attn_kernel<<<dim3(Sc, Bc, Hc), dim3(256), 0, stream>>>(
        q, k_t, v_t, mask, obuf);

    out_proj_kernel<<<dim3(BSc / 64, Dc / 64), dim3(16, 16), 0, stream>>>(
        obuf, Wo, bo, out);
}

// Round 2
// 969.048 us; speedup vs baseline: 3.0919x; 3.0919x over previous
//
#include <hip/hip_runtime.h>
#include <hip/hip_bf16.h>
#include <cmath>

// Problem constants
constexpr int Bc  = 2;
constexpr int Sc  = 2048;
constexpr int Dc  = 768;
constexpr int Hc  = 12;
constexpr int Ec  = 64;          // d_head
constexpr int BSc = Bc * Sc;     // 4096

typedef _Float16 f16;
typedef __attribute__((ext_vector_type(8)))  _Float16 half8;   // MFMA A/B frag (4 VGPR)
typedef __attribute__((ext_vector_type(16))) float    floatx16; // MFMA C/D (16 VGPR)

// ---------------------------------------------------------------------------
// Kernel 1: QKV projection (fp32 math, fp16 outputs).
// q,k stored [H,B,S,E] fp16; v stored TRANSPOSED [H,B,E,S] fp16.
// ---------------------------------------------------------------------------
__global__ __launch_bounds__(256, 2) void qkv_proj_kernel(
    const float* __restrict__ x,
    const float* __restrict__ Wq, const float* __restrict__ bq,
    const float* __restrict__ Wk, const float* __restrict__ bk,
    const float* __restrict__ Wv, const float* __restrict__ bv,
    f16* __restrict__ q_out, f16* __restrict__ k_out, f16* __restrict__ vt_out)
{
    __shared__ __align__(16) float Xs[64][68];  // transposed: Xs[k][row]
    __shared__ __align__(16) float Ws[64][68];  // Ws[k][col]
    __shared__ __align__(16) float Cs[64][68];  // staging for transposed v store

    const int stile = blockIdx.x;
    const int h     = blockIdx.y;
    const int proj  = blockIdx.z;        // 0=q 1=k 2=v
    const int tx = threadIdx.x;
    const int ty = threadIdx.y;
    const int t  = ty * 16 + tx;
    const int s0 = stile * 64;

    const float* W; const float* bias;
    if (proj == 0)      { W = Wq; bias = bq; }
    else if (proj == 1) { W = Wk; bias = bk; }
    else                { W = Wv; bias = bv; }

    const int lc = t & 63;
    const int lr = t >> 6;

    float acc[4][4];
    #pragma unroll
    for (int i = 0; i < 4; ++i)
        #pragma unroll
        for (int j = 0; j < 4; ++j) acc[i][j] = 0.f;

    for (int ktile = 0; ktile < Dc / 64; ++ktile) {
        #pragma unroll
        for (int rr = 0; rr < 16; ++rr) {
            const int r = lr + rr * 4;
            Xs[lc][r] = x[(size_t)(s0 + r) * Dc + ktile * 64 + lc];
            Ws[r][lc] = W[(size_t)(h * Dc + ktile * 64 + r) * Ec + lc];
        }
        __syncthreads();
        #pragma unroll
        for (int kk = 0; kk < 64; ++kk) {
            const float4 av  = *(const float4*)&Xs[kk][ty * 4];
            const float4 bv4 = *(const float4*)&Ws[kk][tx * 4];
            const float a_[4] = {av.x, av.y, av.z, av.w};
            const float b_[4] = {bv4.x, bv4.y, bv4.z, bv4.w};
            #pragma unroll
            for (int i = 0; i < 4; ++i)
                #pragma unroll
                for (int j = 0; j < 4; ++j)
                    acc[i][j] += a_[i] * b_[j];
        }
        __syncthreads();
    }

    if (proj <= 1) {
        f16* dst = (proj == 0) ? q_out : k_out;
        #pragma unroll
        for (int i = 0; i < 4; ++i) {
            const int row = ty * 4 + i;
            const size_t off = ((size_t)h * BSc + s0 + row) * Ec + tx * 4;
            #pragma unroll
            for (int j = 0; j < 4; ++j)
                dst[off + j] = (f16)(acc[i][j] + bias[h * Ec + tx * 4 + j]);
        }
    } else {
        #pragma unroll
        for (int i = 0; i < 4; ++i)
            #pragma unroll
            for (int j = 0; j < 4; ++j)
                Cs[ty * 4 + i][tx * 4 + j] = acc[i][j] + bias[h * Ec + tx * 4 + j];
        __syncthreads();
        const int b   = s0 / Sc;
        const int sin = s0 % Sc;
        const size_t base = ((size_t)(h * Bc + b) * Ec) * Sc;
        #pragma unroll
        for (int it = 0; it < 16; ++it) {
            const int e = lr + it * 4;
            vt_out[base + (size_t)e * Sc + sin + lc] = (f16)Cs[lc][e];
        }
    }
}

// ---------------------------------------------------------------------------
// Kernel 2: fp16 MFMA flash attention.
// Grid (S/64, B, H); block 256 = 4 waves. wave = rg (row-group of 32 rows)
// x kh (key half of 1024 keys). 32x32x16_f16 MFMA. Online softmax in C-layout:
// col = lane&31, row = (reg&3) + 8*(reg>>2) + 4*(lane>>5).
// P goes C-layout -> LDS -> A-layout (row stride 40 halves: b128 conflict-free).
// Key-halves merged via LDS at the end (flash combine).
// ---------------------------------------------------------------------------
__global__ __launch_bounds__(256, 2) void flash_attn_kernel(
    const f16* __restrict__ q16, const f16* __restrict__ k16,
    const f16* __restrict__ v16t, const float* __restrict__ mask,
    float* __restrict__ obuf)
{
    __shared__ _Float16 Plds[4][32][40];     // per-wave private P tile
    __shared__ float MLds[2][64][17];
    __shared__ float LLds[2][64][17];
    __shared__ float OLds[2][64][33];

    const int rb   = blockIdx.x;
    const int b    = blockIdx.y;
    const int h    = blockIdx.z;
    const int hb   = h * Bc + b;
    const int t    = threadIdx.x;
    const int wave = t >> 6;
    const int lane = t & 63;
    const int rg   = wave & 1;   // row group
    const int kh   = wave >> 1;  // key half
    const int col  = lane & 31;
    const int hf   = lane >> 5;
    const int row0 = rb * 64 + rg * 32;

    const f16* qb = q16 + ((size_t)hb * Sc + row0) * Ec;
    const f16* kb = k16 + (size_t)hb * Sc * Ec;
    const f16* vb = v16t + (size_t)hb * Ec * Sc;

    // Q A-frags for the 4 K-steps of E=64 (each: A[m=col][k=ks*16 + hf*8 + j])
    half8 qfrag[4];
    #pragma unroll
    for (int ks = 0; ks < 4; ++ks)
        qfrag[ks] = *(const half8*)(qb + (size_t)col * Ec + ks * 16 + hf * 8);

    floatx16 o0, o1;
    float mrun[16], lrun[16];
    #pragma unroll
    for (int i = 0; i < 16; ++i) { o0[i] = 0.f; o1[i] = 0.f; mrun[i] = -1e30f; lrun[i] = 0.f; }

    const float* mbase = mask + ((size_t)hb * Sc + row0) * Sc + col;
    const int key_base = kh * (Sc / 2);
    constexpr int NT = (Sc / 2) / 32;   // 32 tiles

    // prefetch mask tile 0
    float mbuf[16];
    #pragma unroll
    for (int i = 0; i < 16; ++i) {
        const int r = (i & 3) + 8 * (i >> 2) + 4 * hf;
        mbuf[i] = mbase[(size_t)r * Sc + key_base];
    }

    for (int kt = 0; kt < NT; ++kt) {
        const int key0 = key_base + kt * 32;

        float mcur[16];
        #pragma unroll
        for (int i = 0; i < 16; ++i) mcur[i] = mbuf[i];
        if (kt + 1 < NT) {
            #pragma unroll
            for (int i = 0; i < 16; ++i) {
                const int r = (i & 3) + 8 * (i >> 2) + 4 * hf;
                mbuf[i] = mbase[(size_t)r * Sc + key0 + 32];
            }
        }

        // ---- S = Q @ K^T  (32 rows x 32 keys) ----
        floatx16 c;
        #pragma unroll
        for (int i = 0; i < 16; ++i) c[i] = 0.f;
        #pragma unroll
        for (int ks = 0; ks < 4; ++ks) {
            half8 kf = *(const half8*)(kb + (size_t)(key0 + col) * Ec + ks * 16 + hf * 8);
            c = __builtin_amdgcn_mfma_f32_32x32x16_f16(qfrag[ks], kf, c, 0, 0, 0);
        }

        // ---- online softmax ----
        float p[16];
        #pragma unroll
        for (int i = 0; i < 16; ++i) {
            const float s = c[i] + mcur[i];
            float v = s;
            v = fmaxf(v, __shfl_xor(v, 1));
            v = fmaxf(v, __shfl_xor(v, 2));
            v = fmaxf(v, __shfl_xor(v, 4));
            v = fmaxf(v, __shfl_xor(v, 8));
            v = fmaxf(v, __shfl_xor(v, 16));
            const float mnew  = fmaxf(mrun[i], v);
            const float alpha = __expf(mrun[i] - mnew);
            const float pe    = __expf(s - mnew);
            mrun[i] = mnew;
            float su = pe;
            su += __shfl_xor(su, 1);
            su += __shfl_xor(su, 2);
            su += __shfl_xor(su, 4);
            su += __shfl_xor(su, 8);
            su += __shfl_xor(su, 16);
            lrun[i] = lrun[i] * alpha + su;
            o0[i] *= alpha;
            o1[i] *= alpha;
            p[i] = pe;
        }

        // ---- P (C-layout) -> LDS ----
        #pragma unroll
        for (int i = 0; i < 16; ++i) {
            const int r = (i & 3) + 8 * (i >> 2) + 4 * hf;
            Plds[wave][r][col] = (f16)p[i];
        }
        // same-wave RAW through LDS: force drain (per-wave private slice, no barrier)
        asm volatile("s_waitcnt lgkmcnt(0)" ::: "memory");

        // ---- O += P @ V  (2 K-steps of 16 keys, e in two 32-chunks) ----
        #pragma unroll
        for (int ks = 0; ks < 2; ++ks) {
            half8 pf = *(const half8*)(&Plds[wave][col][ks * 16 + hf * 8]);
            half8 v0 = *(const half8*)(vb + (size_t)col        * Sc + key0 + ks * 16 + hf * 8);
            half8 v1 = *(const half8*)(vb + (size_t)(32 + col) * Sc + key0 + ks * 16 + hf * 8);
            o0 = __builtin_amdgcn_mfma_f32_32x32x16_f16(pf, v0, o0, 0, 0, 0);
            o1 = __builtin_amdgcn_mfma_f32_32x32x16_f16(pf, v1, o1, 0, 0, 0);
        }
    }

    // ---- combine the two key-halves ----
    if (kh == 1) {
        #pragma unroll
        for (int i = 0; i < 16; ++i) {
            MLds[rg][lane][i]      = mrun[i];
            LLds[rg][lane][i]      = lrun[i];
            OLds[rg][lane][i]      = o0[i];
            OLds[rg][lane][16 + i] = o1[i];
        }
    }
    __syncthreads();
    if (kh == 0) {
        #pragma unroll
        for (int i = 0; i < 16; ++i) {
            const float m2 = MLds[rg][lane][i];
            const float l2 = LLds[rg][lane][i];
            const float mn = fmaxf(mrun[i], m2);
            const float a1 = __expf(mrun[i] - mn);
            const float a2 = __expf(m2 - mn);
            const float inv = 1.f / (lrun[i] * a1 + l2 * a2);
            const float r0 = (o0[i] * a1 + OLds[rg][lane][i]      * a2) * inv;
            const float r1 = (o1[i] * a1 + OLds[rg][lane][16 + i] * a2) * inv;
            const int r = (i & 3) + 8 * (i >> 2) + 4 * hf;
            const size_t orow = ((size_t)b * Sc + row0 + r) * Dc + h * Ec;
            obuf[orow + col]      = r0;
            obuf[orow + 32 + col] = r1;
        }
    }
}

// ---------------------------------------------------------------------------
// Kernel 3: output projection (fp32). out = obuf @ Wo + bo
// ---------------------------------------------------------------------------
__global__ __launch_bounds__(256, 2) void out_proj_kernel(
    const float* __restrict__ obuf, const float* __restrict__ Wo,
    const float* __restrict__ bo, float* __restrict__ out)
{
    __shared__ __align__(16) float Xs[64][68];
    __shared__ __align__(16) float Ws[64][68];

    const int rt = blockIdx.x;
    const int ct = blockIdx.y;
    const int tx = threadIdx.x, ty = threadIdx.y;
    const int t  = ty * 16 + tx;
    const int lc = t & 63, lr = t >> 6;

    float acc[4][4];
    #pragma unroll
    for (int i = 0; i < 4; ++i)
        #pragma unroll
        for (int j = 0; j < 4; ++j) acc[i][j] = 0.f;

    for (int ktile = 0; ktile < Dc / 64; ++ktile) {
        #pragma unroll
        for (int rr = 0; rr < 16; ++rr) {
            const int r = lr + rr * 4;
            Xs[lc][r] = obuf[(size_t)(rt * 64 + r) * Dc + ktile * 64 + lc];
            Ws[r][lc] = Wo[(size_t)(ktile * 64 + r) * Dc + ct * 64 + lc];
        }
        __syncthreads();
        #pragma unroll
        for (int kk = 0; kk < 64; ++kk) {
            const float4 av  = *(const float4*)&Xs[kk][ty * 4];
            const float4 bv4 = *(const float4*)&Ws[kk][tx * 4];
            const float a_[4] = {av.x, av.y, av.z, av.w};
            const float b_[4] = {bv4.x, bv4.y, bv4.z, bv4.w};
            #pragma unroll
            for (int i = 0; i < 4; ++i)
                #pragma unroll
                for (int j = 0; j < 4; ++j)
                    acc[i][j] += a_[i] * b_[j];
        }
        __syncthreads();
    }

    #pragma unroll
    for (int i = 0; i < 4; ++i) {
        const int row = rt * 64 + ty * 4 + i;
        #pragma unroll
        for (int j = 0; j < 4; ++j) {
            const int col = ct * 64 + tx * 4 + j;
            out[(size_t)row * Dc + col] = acc[i][j] + bo[col];
        }
    }
}

// ---------------------------------------------------------------------------
extern "C" void kernel_launch(void* const* d_in, const int* in_sizes, int n_in,
                              void* d_out, int out_size, void* d_ws, size_t ws_size,
                              hipStream_t stream)
{
    const float* x    = (const float*)d_in[0];
    const float* mask = (const float*)d_in[1];
    const float* Wq   = (const float*)d_in[2];
    const float* bq   = (const float*)d_in[3];
    const float* Wk   = (const float*)d_in[4];
    const float* bk   = (const float*)d_in[5];
    const float* Wv   = (const float*)d_in[6];
    const float* bv   = (const float*)d_in[7];
    const float* Wo   = (const float*)d_in[8];
    const float* bo   = (const float*)d_in[9];
    float* out = (float*)d_out;

    // workspace: q16 | k16 | v16t (fp16, each H*B*S*E) then obuf (fp32 B*S*D)
    constexpr size_t NQ = (size_t)Hc * Bc * Sc * Ec;  // 3,145,728
    f16* q16  = (f16*)d_ws;
    f16* k16  = q16 + NQ;
    f16* v16t = k16 + NQ;
    float* obuf = (float*)(v16t + NQ);

    qkv_proj_kernel<<<dim3(BSc / 64, Hc, 3), dim3(16, 16), 0, stream>>>(
        x, Wq, bq, Wk, bk, Wv, bv, q16, k16, v16t);

    flash_attn_kernel<<<dim3(Sc / 64, Bc, Hc), dim3(256), 0, stream>>>(
        q16, k16, v16t, mask, obuf);

    out_proj_kernel<<<dim3(BSc / 64, Dc / 64), dim3(16, 16), 0, stream>>>(
        obuf, Wo, bo, out);
}

// Round 3
// 740.953 us; speedup vs baseline: 4.0437x; 1.3078x over previous
//
#include <hip/hip_runtime.h>
#include <hip/hip_bf16.h>
#include <cmath>

// Problem constants
constexpr int Bc  = 2;
constexpr int Sc  = 2048;
constexpr int Dc  = 768;
constexpr int Hc  = 12;
constexpr int Ec  = 64;          // d_head
constexpr int BSc = Bc * Sc;     // 4096

typedef _Float16 f16;
typedef __attribute__((ext_vector_type(8)))  _Float16 half8;    // MFMA A/B frag (4 VGPR)
typedef __attribute__((ext_vector_type(16))) float    floatx16; // MFMA C/D (16 VGPR)

// ---------------------------------------------------------------------------
// Kernel 0: prep — x fp32->fp16 copy; W transposes into B-operand [n][k] fp16;
// concatenated qkv bias. Segmented by blockIdx.x.
//   blocks [0,1536):    x convert (2048 elems/block)
//   blocks [1536,1968): qkv weight transpose (proj,h,dtile) 64x64 tiles
//   blocks [1968,2112): Wo transpose (12x12 tiles of 64x64)
//   blocks [2112,2121): bias concat
// ---------------------------------------------------------------------------
__global__ __launch_bounds__(256) void prep_kernel(
    const float* __restrict__ x,
    const float* __restrict__ Wq, const float* __restrict__ Wk, const float* __restrict__ Wv,
    const float* __restrict__ bq, const float* __restrict__ bk, const float* __restrict__ bv,
    const float* __restrict__ Wo,
    f16* __restrict__ x16, f16* __restrict__ Wt16, f16* __restrict__ Wot16,
    float* __restrict__ bias_cat)
{
    __shared__ __align__(16) float Ts[64][65];
    const int t = threadIdx.x;
    int bid = blockIdx.x;

    if (bid < 1536) {          // ---- x convert ----
        const size_t base = (size_t)bid * 2048 + t * 8;
        const float4 v0 = *(const float4*)(x + base);
        const float4 v1 = *(const float4*)(x + base + 4);
        half8 hv;
        hv[0] = (f16)v0.x; hv[1] = (f16)v0.y; hv[2] = (f16)v0.z; hv[3] = (f16)v0.w;
        hv[4] = (f16)v1.x; hv[5] = (f16)v1.y; hv[6] = (f16)v1.z; hv[7] = (f16)v1.w;
        *(half8*)(x16 + base) = hv;
        return;
    }
    bid -= 1536;
    if (bid < 432) {           // ---- qkv weight transpose: W[h][d][e] -> Wt[(p*768+h*64+e)][d]
        const int proj = bid / 144, rem = bid % 144, h = rem / 12, dt = rem % 12;
        const float* W = ((proj == 0) ? Wq : (proj == 1) ? Wk : Wv) + (size_t)h * Dc * Ec;
        const int c = t & 63, rr = t >> 6;
        #pragma unroll
        for (int r0 = 0; r0 < 64; r0 += 4) {
            const int d = rr + r0;
            Ts[d][c] = W[(size_t)(dt * 64 + d) * Ec + c];   // coalesced over e=c
        }
        __syncthreads();
        #pragma unroll
        for (int r0 = 0; r0 < 64; r0 += 4) {
            const int e = rr + r0;
            Wt16[(size_t)(proj * 768 + h * 64 + e) * Dc + dt * 64 + c] = (f16)Ts[c][e];
        }
        return;
    }
    bid -= 432;
    if (bid < 144) {           // ---- Wo transpose: Wo[din][dout] -> Wot[dout][din]
        const int rt = bid / 12, ct = bid % 12;
        const int c = t & 63, rr = t >> 6;
        #pragma unroll
        for (int r0 = 0; r0 < 64; r0 += 4) {
            const int d = rr + r0;
            Ts[d][c] = Wo[(size_t)(rt * 64 + d) * Dc + ct * 64 + c];
        }
        __syncthreads();
        #pragma unroll
        for (int r0 = 0; r0 < 64; r0 += 4) {
            const int e = rr + r0;
            Wot16[(size_t)(ct * 64 + e) * Dc + rt * 64 + c] = (f16)Ts[c][e];
        }
        return;
    }
    bid -= 144;
    {                          // ---- bias concat ----
        const int g = bid * 256 + t;
        if (g < 3 * 768) {
            const int proj = g / 768, idx = g % 768;
            const float* bb = (proj == 0) ? bq : (proj == 1) ? bk : bv;
            bias_cat[g] = bb[idx];
        }
    }
}

// ---------------------------------------------------------------------------
// Kernel 1: QKV GEMM (fp16 MFMA).  C[4096,2304] = x16 @ Wt16^T + bias_cat.
// 128x128 tile, 256 thr = 4 waves (2x2), each wave 64x64 via 2x2 of 32x32x16.
// Epilogue stages C in LDS then scatters: q,k -> [H,B,S,E]; v -> [H,B,E,S].
// N-tiles (128) align with proj (768 each) and head (64) boundaries.
// ---------------------------------------------------------------------------
__global__ __launch_bounds__(256, 2) void gemm_qkv_kernel(
    const f16* __restrict__ x16, const f16* __restrict__ Wt16,
    const float* __restrict__ bias_cat,
    f16* __restrict__ q16, f16* __restrict__ k16, f16* __restrict__ v16t)
{
    __shared__ __align__(16) unsigned char smem[36864];
    f16 (*As)[72]  = (f16(*)[72])smem;              // 128 x 72 halves = 18432 B
    f16 (*Bs)[72]  = (f16(*)[72])(smem + 18432);    // 128 x 72 halves
    f16 (*Cs)[136] = (f16(*)[136])smem;             // 128 x 136 halves = 34816 B (aliases A/B)

    const int t = threadIdx.x;
    const int wave = t >> 6, lane = t & 63;
    const int col = lane & 31, hf = lane >> 5;
    const int wr = wave & 1, wc = wave >> 1;
    const int m0 = blockIdx.x * 128, n0 = blockIdx.y * 128;

    floatx16 c00, c01, c10, c11;
    #pragma unroll
    for (int i = 0; i < 16; ++i) { c00[i] = 0.f; c01[i] = 0.f; c10[i] = 0.f; c11[i] = 0.f; }

    for (int k0 = 0; k0 < Dc; k0 += 64) {
        #pragma unroll
        for (int p = 0; p < 4; ++p) {
            const int cid = p * 256 + t;
            const int row = cid >> 3, seg = cid & 7;
            *(half8*)&As[row][seg * 8] =
                *(const half8*)(x16 + (size_t)(m0 + row) * Dc + k0 + seg * 8);
            *(half8*)&Bs[row][seg * 8] =
                *(const half8*)(Wt16 + (size_t)(n0 + row) * Dc + k0 + seg * 8);
        }
        __syncthreads();
        #pragma unroll
        for (int ks = 0; ks < 4; ++ks) {
            const half8 a0 = *(const half8*)&As[wr * 64 + col][ks * 16 + hf * 8];
            const half8 a1 = *(const half8*)&As[wr * 64 + 32 + col][ks * 16 + hf * 8];
            const half8 b0 = *(const half8*)&Bs[wc * 64 + col][ks * 16 + hf * 8];
            const half8 b1 = *(const half8*)&Bs[wc * 64 + 32 + col][ks * 16 + hf * 8];
            c00 = __builtin_amdgcn_mfma_f32_32x32x16_f16(a0, b0, c00, 0, 0, 0);
            c01 = __builtin_amdgcn_mfma_f32_32x32x16_f16(a0, b1, c01, 0, 0, 0);
            c10 = __builtin_amdgcn_mfma_f32_32x32x16_f16(a1, b0, c10, 0, 0, 0);
            c11 = __builtin_amdgcn_mfma_f32_32x32x16_f16(a1, b1, c11, 0, 0, 0);
        }
        __syncthreads();
    }

    // bias + stage into Cs (fp16)
    const float bias0 = bias_cat[n0 + wc * 64 + col];
    const float bias1 = bias_cat[n0 + wc * 64 + 32 + col];
    #pragma unroll
    for (int i = 0; i < 16; ++i) {
        const int r = (i & 3) + 8 * (i >> 2) + 4 * hf;
        Cs[wr * 64 + r][wc * 64 + col]           = (f16)(c00[i] + bias0);
        Cs[wr * 64 + r][wc * 64 + 32 + col]      = (f16)(c01[i] + bias1);
        Cs[wr * 64 + 32 + r][wc * 64 + col]      = (f16)(c10[i] + bias0);
        Cs[wr * 64 + 32 + r][wc * 64 + 32 + col] = (f16)(c11[i] + bias1);
    }
    __syncthreads();

    const int proj = n0 / 768;
    const int h0   = (n0 - proj * 768) >> 6;   // first of two heads in this tile
    const int b    = m0 >> 11;
    const int s_in = m0 & 2047;

    if (proj < 2) {
        f16* dst = (proj == 0) ? q16 : k16;
        const int row = t >> 1, seg = t & 1;
        const int h = h0 + seg;
        f16* gp = dst + ((size_t)(h * Bc + b) * Sc + s_in + row) * Ec;
        #pragma unroll
        for (int j = 0; j < 8; ++j)
            *(half8*)(gp + j * 8) = *(const half8*)&Cs[row][seg * 64 + j * 8];
    } else {
        const int coln = t & 127, half_ = t >> 7;
        const int seg = coln >> 6, e = coln & 63;
        const int h = h0 + seg;
        f16* gp = v16t + ((size_t)(h * Bc + b) * Ec + e) * Sc + s_in + half_ * 64;
        #pragma unroll
        for (int jb = 0; jb < 8; ++jb) {
            half8 tv;
            #pragma unroll
            for (int j2 = 0; j2 < 8; ++j2)
                tv[j2] = Cs[half_ * 64 + jb * 8 + j2][coln];
            *(half8*)(gp + jb * 8) = tv;
        }
    }
}

// ---------------------------------------------------------------------------
// Kernel 2: fp16 MFMA flash attention (unchanged structure; fp16 obuf output).
// ---------------------------------------------------------------------------
__global__ __launch_bounds__(256, 2) void flash_attn_kernel(
    const f16* __restrict__ q16, const f16* __restrict__ k16,
    const f16* __restrict__ v16t, const float* __restrict__ mask,
    f16* __restrict__ obuf16)
{
    __shared__ _Float16 Plds[4][32][40];
    __shared__ float MLds[2][64][17];
    __shared__ float LLds[2][64][17];
    __shared__ float OLds[2][64][33];

    const int rb   = blockIdx.x;
    const int b    = blockIdx.y;
    const int h    = blockIdx.z;
    const int hb   = h * Bc + b;
    const int t    = threadIdx.x;
    const int wave = t >> 6;
    const int lane = t & 63;
    const int rg   = wave & 1;
    const int kh   = wave >> 1;
    const int col  = lane & 31;
    const int hf   = lane >> 5;
    const int row0 = rb * 64 + rg * 32;

    const f16* qb = q16 + ((size_t)hb * Sc + row0) * Ec;
    const f16* kb = k16 + (size_t)hb * Sc * Ec;
    const f16* vb = v16t + (size_t)hb * Ec * Sc;

    half8 qfrag[4];
    #pragma unroll
    for (int ks = 0; ks < 4; ++ks)
        qfrag[ks] = *(const half8*)(qb + (size_t)col * Ec + ks * 16 + hf * 8);

    floatx16 o0, o1;
    float mrun[16], lrun[16];
    #pragma unroll
    for (int i = 0; i < 16; ++i) { o0[i] = 0.f; o1[i] = 0.f; mrun[i] = -1e30f; lrun[i] = 0.f; }

    const float* mbase = mask + ((size_t)hb * Sc + row0) * Sc + col;
    const int key_base = kh * (Sc / 2);
    constexpr int NT = (Sc / 2) / 32;

    float mbuf[16];
    #pragma unroll
    for (int i = 0; i < 16; ++i) {
        const int r = (i & 3) + 8 * (i >> 2) + 4 * hf;
        mbuf[i] = mbase[(size_t)r * Sc + key_base];
    }

    for (int kt = 0; kt < NT; ++kt) {
        const int key0 = key_base + kt * 32;

        float mcur[16];
        #pragma unroll
        for (int i = 0; i < 16; ++i) mcur[i] = mbuf[i];
        if (kt + 1 < NT) {
            #pragma unroll
            for (int i = 0; i < 16; ++i) {
                const int r = (i & 3) + 8 * (i >> 2) + 4 * hf;
                mbuf[i] = mbase[(size_t)r * Sc + key0 + 32];
            }
        }

        floatx16 c;
        #pragma unroll
        for (int i = 0; i < 16; ++i) c[i] = 0.f;
        #pragma unroll
        for (int ks = 0; ks < 4; ++ks) {
            const half8 kf = *(const half8*)(kb + (size_t)(key0 + col) * Ec + ks * 16 + hf * 8);
            c = __builtin_amdgcn_mfma_f32_32x32x16_f16(qfrag[ks], kf, c, 0, 0, 0);
        }

        float p[16];
        #pragma unroll
        for (int i = 0; i < 16; ++i) {
            const float s = c[i] + mcur[i];
            float v = s;
            v = fmaxf(v, __shfl_xor(v, 1));
            v = fmaxf(v, __shfl_xor(v, 2));
            v = fmaxf(v, __shfl_xor(v, 4));
            v = fmaxf(v, __shfl_xor(v, 8));
            v = fmaxf(v, __shfl_xor(v, 16));
            const float mnew  = fmaxf(mrun[i], v);
            const float alpha = __expf(mrun[i] - mnew);
            const float pe    = __expf(s - mnew);
            mrun[i] = mnew;
            float su = pe;
            su += __shfl_xor(su, 1);
            su += __shfl_xor(su, 2);
            su += __shfl_xor(su, 4);
            su += __shfl_xor(su, 8);
            su += __shfl_xor(su, 16);
            lrun[i] = lrun[i] * alpha + su;
            o0[i] *= alpha;
            o1[i] *= alpha;
            p[i] = pe;
        }

        #pragma unroll
        for (int i = 0; i < 16; ++i) {
            const int r = (i & 3) + 8 * (i >> 2) + 4 * hf;
            Plds[wave][r][col] = (f16)p[i];
        }
        asm volatile("s_waitcnt lgkmcnt(0)" ::: "memory");

        #pragma unroll
        for (int ks = 0; ks < 2; ++ks) {
            const half8 pf = *(const half8*)(&Plds[wave][col][ks * 16 + hf * 8]);
            const half8 v0 = *(const half8*)(vb + (size_t)col        * Sc + key0 + ks * 16 + hf * 8);
            const half8 v1 = *(const half8*)(vb + (size_t)(32 + col) * Sc + key0 + ks * 16 + hf * 8);
            o0 = __builtin_amdgcn_mfma_f32_32x32x16_f16(pf, v0, o0, 0, 0, 0);
            o1 = __builtin_amdgcn_mfma_f32_32x32x16_f16(pf, v1, o1, 0, 0, 0);
        }
    }

    if (kh == 1) {
        #pragma unroll
        for (int i = 0; i < 16; ++i) {
            MLds[rg][lane][i]      = mrun[i];
            LLds[rg][lane][i]      = lrun[i];
            OLds[rg][lane][i]      = o0[i];
            OLds[rg][lane][16 + i] = o1[i];
        }
    }
    __syncthreads();
    if (kh == 0) {
        #pragma unroll
        for (int i = 0; i < 16; ++i) {
            const float m2 = MLds[rg][lane][i];
            const float l2 = LLds[rg][lane][i];
            const float mn = fmaxf(mrun[i], m2);
            const float a1 = __expf(mrun[i] - mn);
            const float a2 = __expf(m2 - mn);
            const float inv = 1.f / (lrun[i] * a1 + l2 * a2);
            const float r0 = (o0[i] * a1 + OLds[rg][lane][i]      * a2) * inv;
            const float r1 = (o1[i] * a1 + OLds[rg][lane][16 + i] * a2) * inv;
            const int r = (i & 3) + 8 * (i >> 2) + 4 * hf;
            const size_t orow = ((size_t)b * Sc + row0 + r) * Dc + h * Ec;
            obuf16[orow + col]      = (f16)r0;
            obuf16[orow + 32 + col] = (f16)r1;
        }
    }
}

// ---------------------------------------------------------------------------
// Kernel 3: output GEMM (fp16 MFMA). out[4096,768] = obuf16 @ Wot16^T + bo.
// 128x64 tile, 4 waves each 32x64 (2x 32x32x16 accumulators). fp32 store.
// ---------------------------------------------------------------------------
__global__ __launch_bounds__(256, 2) void gemm_out_kernel(
    const f16* __restrict__ a16, const f16* __restrict__ Wot16,
    const float* __restrict__ bo, float* __restrict__ out)
{
    __shared__ __align__(16) f16 As[128][72];
    __shared__ __align__(16) f16 Bs[64][72];

    const int t = threadIdx.x;
    const int wave = t >> 6, lane = t & 63;
    const int col = lane & 31, hf = lane >> 5;
    const int m0 = blockIdx.x * 128, n0 = blockIdx.y * 64;

    floatx16 c0, c1;
    #pragma unroll
    for (int i = 0; i < 16; ++i) { c0[i] = 0.f; c1[i] = 0.f; }

    for (int k0 = 0; k0 < Dc; k0 += 64) {
        #pragma unroll
        for (int p = 0; p < 4; ++p) {
            const int cid = p * 256 + t;
            *(half8*)&As[cid >> 3][(cid & 7) * 8] =
                *(const half8*)(a16 + (size_t)(m0 + (cid >> 3)) * Dc + k0 + (cid & 7) * 8);
        }
        #pragma unroll
        for (int p = 0; p < 2; ++p) {
            const int cid = p * 256 + t;
            *(half8*)&Bs[cid >> 3][(cid & 7) * 8] =
                *(const half8*)(Wot16 + (size_t)(n0 + (cid >> 3)) * Dc + k0 + (cid & 7) * 8);
        }
        __syncthreads();
        #pragma unroll
        for (int ks = 0; ks < 4; ++ks) {
            const half8 a  = *(const half8*)&As[wave * 32 + col][ks * 16 + hf * 8];
            const half8 b0 = *(const half8*)&Bs[col][ks * 16 + hf * 8];
            const half8 b1 = *(const half8*)&Bs[32 + col][ks * 16 + hf * 8];
            c0 = __builtin_amdgcn_mfma_f32_32x32x16_f16(a, b0, c0, 0, 0, 0);
            c1 = __builtin_amdgcn_mfma_f32_32x32x16_f16(a, b1, c1, 0, 0, 0);
        }
        __syncthreads();
    }

    const float bo0 = bo[n0 + col], bo1 = bo[n0 + 32 + col];
    #pragma unroll
    for (int i = 0; i < 16; ++i) {
        const int r = (i & 3) + 8 * (i >> 2) + 4 * hf;
        const size_t ro = (size_t)(m0 + wave * 32 + r) * Dc + n0;
        out[ro + col]      = c0[i] + bo0;
        out[ro + 32 + col] = c1[i] + bo1;
    }
}

// ---------------------------------------------------------------------------
extern "C" void kernel_launch(void* const* d_in, const int* in_sizes, int n_in,
                              void* d_out, int out_size, void* d_ws, size_t ws_size,
                              hipStream_t stream)
{
    const float* x    = (const float*)d_in[0];
    const float* mask = (const float*)d_in[1];
    const float* Wq   = (const float*)d_in[2];
    const float* bq   = (const float*)d_in[3];
    const float* Wk   = (const float*)d_in[4];
    const float* bk   = (const float*)d_in[5];
    const float* Wv   = (const float*)d_in[6];
    const float* bv   = (const float*)d_in[7];
    const float* Wo   = (const float*)d_in[8];
    const float* bo   = (const float*)d_in[9];
    float* out = (float*)d_out;

    // workspace layout (halves):
    constexpr size_t NQ = (size_t)Hc * Bc * Sc * Ec;  // 3,145,728
    f16* x16    = (f16*)d_ws;            // 4096*768
    f16* Wt16   = x16 + (size_t)BSc * Dc;          // 2304*768
    f16* Wot16  = Wt16 + (size_t)3 * Dc * Dc;      // 768*768
    f16* q16    = Wot16 + (size_t)Dc * Dc;
    f16* k16    = q16 + NQ;
    f16* v16t   = k16 + NQ;
    f16* obuf16 = v16t + NQ;                       // 4096*768
    float* bias_cat = (float*)(obuf16 + NQ);       // 2304 floats

    prep_kernel<<<2121, 256, 0, stream>>>(x, Wq, Wk, Wv, bq, bk, bv, Wo,
                                          x16, Wt16, Wot16, bias_cat);

    gemm_qkv_kernel<<<dim3(BSc / 128, 2304 / 128), 256, 0, stream>>>(
        x16, Wt16, bias_cat, q16, k16, v16t);

    flash_attn_kernel<<<dim3(Sc / 64, Bc, Hc), 256, 0, stream>>>(
        q16, k16, v16t, mask, obuf16);

    gemm_out_kernel<<<dim3(BSc / 128, Dc / 64), 256, 0, stream>>>(
        obuf16, Wot16, bo, out);
}

// Round 4
// 734.408 us; speedup vs baseline: 4.0797x; 1.0089x over previous
//
#include <hip/hip_runtime.h>
#include <hip/hip_bf16.h>
#include <cmath>

// Problem constants
constexpr int Bc  = 2;
constexpr int Sc  = 2048;
constexpr int Dc  = 768;
constexpr int Hc  = 12;
constexpr int Ec  = 64;          // d_head
constexpr int BSc = Bc * Sc;     // 4096

typedef _Float16 f16;
typedef __attribute__((ext_vector_type(8)))  _Float16 half8;    // MFMA A/B frag (4 VGPR)
typedef __attribute__((ext_vector_type(16))) float    floatx16; // MFMA C/D (16 VGPR)

// ---------------------------------------------------------------------------
// Kernel 0: prep — x fp32->fp16 copy; W transposes into B-operand [n][k] fp16;
// concatenated qkv bias. Segmented by blockIdx.x.
// ---------------------------------------------------------------------------
__global__ __launch_bounds__(256) void prep_kernel(
    const float* __restrict__ x,
    const float* __restrict__ Wq, const float* __restrict__ Wk, const float* __restrict__ Wv,
    const float* __restrict__ bq, const float* __restrict__ bk, const float* __restrict__ bv,
    const float* __restrict__ Wo,
    f16* __restrict__ x16, f16* __restrict__ Wt16, f16* __restrict__ Wot16,
    float* __restrict__ bias_cat)
{
    __shared__ __align__(16) float Ts[64][65];
    const int t = threadIdx.x;
    int bid = blockIdx.x;

    if (bid < 1536) {          // ---- x convert ----
        const size_t base = (size_t)bid * 2048 + t * 8;
        const float4 v0 = *(const float4*)(x + base);
        const float4 v1 = *(const float4*)(x + base + 4);
        half8 hv;
        hv[0] = (f16)v0.x; hv[1] = (f16)v0.y; hv[2] = (f16)v0.z; hv[3] = (f16)v0.w;
        hv[4] = (f16)v1.x; hv[5] = (f16)v1.y; hv[6] = (f16)v1.z; hv[7] = (f16)v1.w;
        *(half8*)(x16 + base) = hv;
        return;
    }
    bid -= 1536;
    if (bid < 432) {           // ---- qkv weight transpose: W[h][d][e] -> Wt[(p*768+h*64+e)][d]
        const int proj = bid / 144, rem = bid % 144, h = rem / 12, dt = rem % 12;
        const float* W = ((proj == 0) ? Wq : (proj == 1) ? Wk : Wv) + (size_t)h * Dc * Ec;
        const int c = t & 63, rr = t >> 6;
        #pragma unroll
        for (int r0 = 0; r0 < 64; r0 += 4) {
            const int d = rr + r0;
            Ts[d][c] = W[(size_t)(dt * 64 + d) * Ec + c];
        }
        __syncthreads();
        #pragma unroll
        for (int r0 = 0; r0 < 64; r0 += 4) {
            const int e = rr + r0;
            Wt16[(size_t)(proj * 768 + h * 64 + e) * Dc + dt * 64 + c] = (f16)Ts[c][e];
        }
        return;
    }
    bid -= 432;
    if (bid < 144) {           // ---- Wo transpose ----
        const int rt = bid / 12, ct = bid % 12;
        const int c = t & 63, rr = t >> 6;
        #pragma unroll
        for (int r0 = 0; r0 < 64; r0 += 4) {
            const int d = rr + r0;
            Ts[d][c] = Wo[(size_t)(rt * 64 + d) * Dc + ct * 64 + c];
        }
        __syncthreads();
        #pragma unroll
        for (int r0 = 0; r0 < 64; r0 += 4) {
            const int e = rr + r0;
            Wot16[(size_t)(ct * 64 + e) * Dc + rt * 64 + c] = (f16)Ts[c][e];
        }
        return;
    }
    bid -= 144;
    {                          // ---- bias concat ----
        const int g = bid * 256 + t;
        if (g < 3 * 768) {
            const int proj = g / 768, idx = g % 768;
            const float* bb = (proj == 0) ? bq : (proj == 1) ? bk : bv;
            bias_cat[g] = bb[idx];
        }
    }
}

// ---------------------------------------------------------------------------
// Kernel 1: QKV GEMM (fp16 MFMA).  C[4096,2304] = x16 @ Wt16^T + bias_cat.
// ---------------------------------------------------------------------------
__global__ __launch_bounds__(256, 2) void gemm_qkv_kernel(
    const f16* __restrict__ x16, const f16* __restrict__ Wt16,
    const float* __restrict__ bias_cat,
    f16* __restrict__ q16, f16* __restrict__ k16, f16* __restrict__ v16t)
{
    __shared__ __align__(16) unsigned char smem[36864];
    f16 (*As)[72]  = (f16(*)[72])smem;
    f16 (*Bs)[72]  = (f16(*)[72])(smem + 18432);
    f16 (*Cs)[136] = (f16(*)[136])smem;

    const int t = threadIdx.x;
    const int wave = t >> 6, lane = t & 63;
    const int col = lane & 31, hf = lane >> 5;
    const int wr = wave & 1, wc = wave >> 1;
    const int m0 = blockIdx.x * 128, n0 = blockIdx.y * 128;

    floatx16 c00, c01, c10, c11;
    #pragma unroll
    for (int i = 0; i < 16; ++i) { c00[i] = 0.f; c01[i] = 0.f; c10[i] = 0.f; c11[i] = 0.f; }

    for (int k0 = 0; k0 < Dc; k0 += 64) {
        #pragma unroll
        for (int p = 0; p < 4; ++p) {
            const int cid = p * 256 + t;
            const int row = cid >> 3, seg = cid & 7;
            *(half8*)&As[row][seg * 8] =
                *(const half8*)(x16 + (size_t)(m0 + row) * Dc + k0 + seg * 8);
            *(half8*)&Bs[row][seg * 8] =
                *(const half8*)(Wt16 + (size_t)(n0 + row) * Dc + k0 + seg * 8);
        }
        __syncthreads();
        #pragma unroll
        for (int ks = 0; ks < 4; ++ks) {
            const half8 a0 = *(const half8*)&As[wr * 64 + col][ks * 16 + hf * 8];
            const half8 a1 = *(const half8*)&As[wr * 64 + 32 + col][ks * 16 + hf * 8];
            const half8 b0 = *(const half8*)&Bs[wc * 64 + col][ks * 16 + hf * 8];
            const half8 b1 = *(const half8*)&Bs[wc * 64 + 32 + col][ks * 16 + hf * 8];
            c00 = __builtin_amdgcn_mfma_f32_32x32x16_f16(a0, b0, c00, 0, 0, 0);
            c01 = __builtin_amdgcn_mfma_f32_32x32x16_f16(a0, b1, c01, 0, 0, 0);
            c10 = __builtin_amdgcn_mfma_f32_32x32x16_f16(a1, b0, c10, 0, 0, 0);
            c11 = __builtin_amdgcn_mfma_f32_32x32x16_f16(a1, b1, c11, 0, 0, 0);
        }
        __syncthreads();
    }

    const float bias0 = bias_cat[n0 + wc * 64 + col];
    const float bias1 = bias_cat[n0 + wc * 64 + 32 + col];
    #pragma unroll
    for (int i = 0; i < 16; ++i) {
        const int r = (i & 3) + 8 * (i >> 2) + 4 * hf;
        Cs[wr * 64 + r][wc * 64 + col]           = (f16)(c00[i] + bias0);
        Cs[wr * 64 + r][wc * 64 + 32 + col]      = (f16)(c01[i] + bias1);
        Cs[wr * 64 + 32 + r][wc * 64 + col]      = (f16)(c10[i] + bias0);
        Cs[wr * 64 + 32 + r][wc * 64 + 32 + col] = (f16)(c11[i] + bias1);
    }
    __syncthreads();

    const int proj = n0 / 768;
    const int h0   = (n0 - proj * 768) >> 6;
    const int b    = m0 >> 11;
    const int s_in = m0 & 2047;

    if (proj < 2) {
        f16* dst = (proj == 0) ? q16 : k16;
        const int row = t >> 1, seg = t & 1;
        const int h = h0 + seg;
        f16* gp = dst + ((size_t)(h * Bc + b) * Sc + s_in + row) * Ec;
        #pragma unroll
        for (int j = 0; j < 8; ++j)
            *(half8*)(gp + j * 8) = *(const half8*)&Cs[row][seg * 64 + j * 8];
    } else {
        const int coln = t & 127, half_ = t >> 7;
        const int seg = coln >> 6, e = coln & 63;
        const int h = h0 + seg;
        f16* gp = v16t + ((size_t)(h * Bc + b) * Ec + e) * Sc + s_in + half_ * 64;
        #pragma unroll
        for (int jb = 0; jb < 8; ++jb) {
            half8 tv;
            #pragma unroll
            for (int j2 = 0; j2 < 8; ++j2)
                tv[j2] = Cs[half_ * 64 + jb * 8 + j2][coln];
            *(half8*)(gp + jb * 8) = tv;
        }
    }
}

// ---------------------------------------------------------------------------
// Kernel 2: fp16 MFMA flash attention — TWO-PASS softmax (no per-tile
// reductions). Pass 1: row max via per-register v_max, one shfl-reduce at end,
// key-half exchange through LDS. Pass 2: p = exp(s - mrow) (<=1, fp16-safe),
// plain register lsum, O accumulates with NO rescaling; one final l-reduce +
// add-only key-half combine.
// ---------------------------------------------------------------------------
__global__ __launch_bounds__(256, 3) void flash_attn_kernel(
    const f16* __restrict__ q16, const f16* __restrict__ k16,
    const f16* __restrict__ v16t, const float* __restrict__ mask,
    f16* __restrict__ obuf16)
{
    __shared__ _Float16 Plds[4][32][40];
    __shared__ float Msh[2][2][32];      // [kh][rg][row] partial row max
    __shared__ float Lsh[2][32];         // [rg][row] kh==1 row sums
    __shared__ float OLsh[2][64][33];    // [rg][lane][reg] kh==1 O staging

    const int rb   = blockIdx.x;
    const int b    = blockIdx.y;
    const int h    = blockIdx.z;
    const int hb   = h * Bc + b;
    const int t    = threadIdx.x;
    const int wave = t >> 6;
    const int lane = t & 63;
    const int rg   = wave & 1;   // row group
    const int kh   = wave >> 1;  // key half
    const int col  = lane & 31;
    const int hf   = lane >> 5;
    const int row0 = rb * 64 + rg * 32;

    const f16* qb = q16 + ((size_t)hb * Sc + row0) * Ec;
    const f16* kb = k16 + (size_t)hb * Sc * Ec;
    const f16* vb = v16t + (size_t)hb * Ec * Sc;

    half8 qfrag[4];
    #pragma unroll
    for (int ks = 0; ks < 4; ++ks)
        qfrag[ks] = *(const half8*)(qb + (size_t)col * Ec + ks * 16 + hf * 8);

    const int key_base = kh * (Sc / 2);
    constexpr int NT = (Sc / 2) / 32;   // 32 tiles

    // ======== PASS 1: row max (no mask needed: mask <= 0 keeps exp <= 1) ====
    float vmax[16];
    #pragma unroll
    for (int i = 0; i < 16; ++i) vmax[i] = -3e38f;

    for (int kt = 0; kt < NT; ++kt) {
        const int key0 = key_base + kt * 32;
        floatx16 c;
        #pragma unroll
        for (int i = 0; i < 16; ++i) c[i] = 0.f;
        #pragma unroll
        for (int ks = 0; ks < 4; ++ks) {
            const half8 kf = *(const half8*)(kb + (size_t)(key0 + col) * Ec + ks * 16 + hf * 8);
            c = __builtin_amdgcn_mfma_f32_32x32x16_f16(qfrag[ks], kf, c, 0, 0, 0);
        }
        #pragma unroll
        for (int i = 0; i < 16; ++i) vmax[i] = fmaxf(vmax[i], c[i]);
    }
    // one reduction across the 32 cols (within each 32-lane half)
    #pragma unroll
    for (int i = 0; i < 16; ++i) {
        float v = vmax[i];
        v = fmaxf(v, __shfl_xor(v, 1));
        v = fmaxf(v, __shfl_xor(v, 2));
        v = fmaxf(v, __shfl_xor(v, 4));
        v = fmaxf(v, __shfl_xor(v, 8));
        v = fmaxf(v, __shfl_xor(v, 16));
        vmax[i] = v;
    }
    // exchange with partner key-half wave
    if (col == 0) {
        #pragma unroll
        for (int i = 0; i < 16; ++i) {
            const int r = (i & 3) + 8 * (i >> 2) + 4 * hf;
            Msh[kh][rg][r] = vmax[i];
        }
    }
    __syncthreads();
    float mrow[16];
    #pragma unroll
    for (int i = 0; i < 16; ++i) {
        const int r = (i & 3) + 8 * (i >> 2) + 4 * hf;
        mrow[i] = fmaxf(vmax[i], Msh[1 - kh][rg][r]);
    }

    // ======== PASS 2: exp + PV, no rescaling ================================
    floatx16 o0, o1;
    float lsum[16];
    #pragma unroll
    for (int i = 0; i < 16; ++i) { o0[i] = 0.f; o1[i] = 0.f; lsum[i] = 0.f; }

    const float* mbase = mask + ((size_t)hb * Sc + row0) * Sc + col;

    float mbuf[16];
    #pragma unroll
    for (int i = 0; i < 16; ++i) {
        const int r = (i & 3) + 8 * (i >> 2) + 4 * hf;
        mbuf[i] = mbase[(size_t)r * Sc + key_base];
    }

    for (int kt = 0; kt < NT; ++kt) {
        const int key0 = key_base + kt * 32;

        float mcur[16];
        #pragma unroll
        for (int i = 0; i < 16; ++i) mcur[i] = mbuf[i];
        if (kt + 1 < NT) {
            #pragma unroll
            for (int i = 0; i < 16; ++i) {
                const int r = (i & 3) + 8 * (i >> 2) + 4 * hf;
                mbuf[i] = mbase[(size_t)r * Sc + key0 + 32];
            }
        }

        floatx16 c;
        #pragma unroll
        for (int i = 0; i < 16; ++i) c[i] = 0.f;
        #pragma unroll
        for (int ks = 0; ks < 4; ++ks) {
            const half8 kf = *(const half8*)(kb + (size_t)(key0 + col) * Ec + ks * 16 + hf * 8);
            c = __builtin_amdgcn_mfma_f32_32x32x16_f16(qfrag[ks], kf, c, 0, 0, 0);
        }

        #pragma unroll
        for (int i = 0; i < 16; ++i) {
            const float p = __expf(c[i] + mcur[i] - mrow[i]);   // <= 1: fp16-safe
            lsum[i] += p;
            const int r = (i & 3) + 8 * (i >> 2) + 4 * hf;
            Plds[wave][r][col] = (f16)p;
        }
        asm volatile("s_waitcnt lgkmcnt(0)" ::: "memory");

        #pragma unroll
        for (int ks = 0; ks < 2; ++ks) {
            const half8 pf = *(const half8*)(&Plds[wave][col][ks * 16 + hf * 8]);
            const half8 v0 = *(const half8*)(vb + (size_t)col        * Sc + key0 + ks * 16 + hf * 8);
            const half8 v1 = *(const half8*)(vb + (size_t)(32 + col) * Sc + key0 + ks * 16 + hf * 8);
            o0 = __builtin_amdgcn_mfma_f32_32x32x16_f16(pf, v0, o0, 0, 0, 0);
            o1 = __builtin_amdgcn_mfma_f32_32x32x16_f16(pf, v1, o1, 0, 0, 0);
        }
    }

    // final l reduction (once)
    #pragma unroll
    for (int i = 0; i < 16; ++i) {
        float v = lsum[i];
        v += __shfl_xor(v, 1);
        v += __shfl_xor(v, 2);
        v += __shfl_xor(v, 4);
        v += __shfl_xor(v, 8);
        v += __shfl_xor(v, 16);
        lsum[i] = v;
    }

    // add-only key-half combine
    if (kh == 1) {
        if (col == 0) {
            #pragma unroll
            for (int i = 0; i < 16; ++i) {
                const int r = (i & 3) + 8 * (i >> 2) + 4 * hf;
                Lsh[rg][r] = lsum[i];
            }
        }
        #pragma unroll
        for (int i = 0; i < 16; ++i) {
            OLsh[rg][lane][i]      = o0[i];
            OLsh[rg][lane][16 + i] = o1[i];
        }
    }
    __syncthreads();
    if (kh == 0) {
        #pragma unroll
        for (int i = 0; i < 16; ++i) {
            const int r = (i & 3) + 8 * (i >> 2) + 4 * hf;
            const float inv = 1.f / (lsum[i] + Lsh[rg][r]);
            const float r0 = (o0[i] + OLsh[rg][lane][i])      * inv;
            const float r1 = (o1[i] + OLsh[rg][lane][16 + i]) * inv;
            const size_t orow = ((size_t)b * Sc + row0 + r) * Dc + h * Ec;
            obuf16[orow + col]      = (f16)r0;
            obuf16[orow + 32 + col] = (f16)r1;
        }
    }
}

// ---------------------------------------------------------------------------
// Kernel 3: output GEMM (fp16 MFMA). out[4096,768] = obuf16 @ Wot16^T + bo.
// ---------------------------------------------------------------------------
__global__ __launch_bounds__(256, 2) void gemm_out_kernel(
    const f16* __restrict__ a16, const f16* __restrict__ Wot16,
    const float* __restrict__ bo, float* __restrict__ out)
{
    __shared__ __align__(16) f16 As[128][72];
    __shared__ __align__(16) f16 Bs[64][72];

    const int t = threadIdx.x;
    const int wave = t >> 6, lane = t & 63;
    const int col = lane & 31, hf = lane >> 5;
    const int m0 = blockIdx.x * 128, n0 = blockIdx.y * 64;

    floatx16 c0, c1;
    #pragma unroll
    for (int i = 0; i < 16; ++i) { c0[i] = 0.f; c1[i] = 0.f; }

    for (int k0 = 0; k0 < Dc; k0 += 64) {
        #pragma unroll
        for (int p = 0; p < 4; ++p) {
            const int cid = p * 256 + t;
            *(half8*)&As[cid >> 3][(cid & 7) * 8] =
                *(const half8*)(a16 + (size_t)(m0 + (cid >> 3)) * Dc + k0 + (cid & 7) * 8);
        }
        #pragma unroll
        for (int p = 0; p < 2; ++p) {
            const int cid = p * 256 + t;
            *(half8*)&Bs[cid >> 3][(cid & 7) * 8] =
                *(const half8*)(Wot16 + (size_t)(n0 + (cid >> 3)) * Dc + k0 + (cid & 7) * 8);
        }
        __syncthreads();
        #pragma unroll
        for (int ks = 0; ks < 4; ++ks) {
            const half8 a  = *(const half8*)&As[wave * 32 + col][ks * 16 + hf * 8];
            const half8 b0 = *(const half8*)&Bs[col][ks * 16 + hf * 8];
            const half8 b1 = *(const half8*)&Bs[32 + col][ks * 16 + hf * 8];
            c0 = __builtin_amdgcn_mfma_f32_32x32x16_f16(a, b0, c0, 0, 0, 0);
            c1 = __builtin_amdgcn_mfma_f32_32x32x16_f16(a, b1, c1, 0, 0, 0);
        }
        __syncthreads();
    }

    const float bo0 = bo[n0 + col], bo1 = bo[n0 + 32 + col];
    #pragma unroll
    for (int i = 0; i < 16; ++i) {
        const int r = (i & 3) + 8 * (i >> 2) + 4 * hf;
        const size_t ro = (size_t)(m0 + wave * 32 + r) * Dc + n0;
        out[ro + col]      = c0[i] + bo0;
        out[ro + 32 + col] = c1[i] + bo1;
    }
}

// ---------------------------------------------------------------------------
extern "C" void kernel_launch(void* const* d_in, const int* in_sizes, int n_in,
                              void* d_out, int out_size, void* d_ws, size_t ws_size,
                              hipStream_t stream)
{
    const float* x    = (const float*)d_in[0];
    const float* mask = (const float*)d_in[1];
    const float* Wq   = (const float*)d_in[2];
    const float* bq   = (const float*)d_in[3];
    const float* Wk   = (const float*)d_in[4];
    const float* bk   = (const float*)d_in[5];
    const float* Wv   = (const float*)d_in[6];
    const float* bv   = (const float*)d_in[7];
    const float* Wo   = (const float*)d_in[8];
    const float* bo   = (const float*)d_in[9];
    float* out = (float*)d_out;

    constexpr size_t NQ = (size_t)Hc * Bc * Sc * Ec;  // 3,145,728
    f16* x16    = (f16*)d_ws;                      // 4096*768
    f16* Wt16   = x16 + (size_t)BSc * Dc;          // 2304*768
    f16* Wot16  = Wt16 + (size_t)3 * Dc * Dc;      // 768*768
    f16* q16    = Wot16 + (size_t)Dc * Dc;
    f16* k16    = q16 + NQ;
    f16* v16t   = k16 + NQ;
    f16* obuf16 = v16t + NQ;                       // 4096*768
    float* bias_cat = (float*)(obuf16 + NQ);       // 2304 floats

    prep_kernel<<<2121, 256, 0, stream>>>(x, Wq, Wk, Wv, bq, bk, bv, Wo,
                                          x16, Wt16, Wot16, bias_cat);

    gemm_qkv_kernel<<<dim3(BSc / 128, 2304 / 128), 256, 0, stream>>>(
        x16, Wt16, bias_cat, q16, k16, v16t);

    flash_attn_kernel<<<dim3(Sc / 64, Bc, Hc), 256, 0, stream>>>(
        q16, k16, v16t, mask, obuf16);

    gemm_out_kernel<<<dim3(BSc / 128, Dc / 64), 256, 0, stream>>>(
        obuf16, Wot16, bo, out);
}

// Round 5
// 684.060 us; speedup vs baseline: 4.3800x; 1.0736x over previous
//
#include <hip/hip_runtime.h>
#include <hip/hip_bf16.h>
#include <cmath>

// Problem constants
constexpr int Bc  = 2;
constexpr int Sc  = 2048;
constexpr int Dc  = 768;
constexpr int Hc  = 12;
constexpr int Ec  = 64;          // d_head
constexpr int BSc = Bc * Sc;     // 4096

typedef _Float16 f16;
typedef __attribute__((ext_vector_type(8)))  _Float16 half8;    // MFMA A/B frag (4 VGPR)
typedef __attribute__((ext_vector_type(16))) float    floatx16; // MFMA C/D (16 VGPR)

typedef __attribute__((address_space(3))) void       lds_void;
typedef __attribute__((address_space(1))) const void glb_cvoid;

// K swizzle: blob per (hb, kt(64), ks(4)), 512 halves: lane(hf*32+col)*8+j =
//   K[hb][key=kt*32+col][e=ks*16+hf*8+j]
// V swizzle: blob per (hb, kt(64), ks2(2), vh(2)), 512 halves: lane*8+j =
//   V[hb][key=kt*32+ks2*16+hf*8+j][e=vh*32+col]   (i.e. V^T fragment order)

// ---------------------------------------------------------------------------
// Kernel 0: prep — x fp32->fp16; W transposes to B-operand [n][k] fp16; bias.
// ---------------------------------------------------------------------------
__global__ __launch_bounds__(256) void prep_kernel(
    const float* __restrict__ x,
    const float* __restrict__ Wq, const float* __restrict__ Wk, const float* __restrict__ Wv,
    const float* __restrict__ bq, const float* __restrict__ bk, const float* __restrict__ bv,
    const float* __restrict__ Wo,
    f16* __restrict__ x16, f16* __restrict__ Wt16, f16* __restrict__ Wot16,
    float* __restrict__ bias_cat)
{
    __shared__ __align__(16) float Ts[64][65];
    const int t = threadIdx.x;
    int bid = blockIdx.x;

    if (bid < 1536) {          // ---- x convert ----
        const size_t base = (size_t)bid * 2048 + t * 8;
        const float4 v0 = *(const float4*)(x + base);
        const float4 v1 = *(const float4*)(x + base + 4);
        half8 hv;
        hv[0] = (f16)v0.x; hv[1] = (f16)v0.y; hv[2] = (f16)v0.z; hv[3] = (f16)v0.w;
        hv[4] = (f16)v1.x; hv[5] = (f16)v1.y; hv[6] = (f16)v1.z; hv[7] = (f16)v1.w;
        *(half8*)(x16 + base) = hv;
        return;
    }
    bid -= 1536;
    if (bid < 432) {           // ---- qkv weight transpose ----
        const int proj = bid / 144, rem = bid % 144, h = rem / 12, dt = rem % 12;
        const float* W = ((proj == 0) ? Wq : (proj == 1) ? Wk : Wv) + (size_t)h * Dc * Ec;
        const int c = t & 63, rr = t >> 6;
        #pragma unroll
        for (int r0 = 0; r0 < 64; r0 += 4) {
            const int d = rr + r0;
            Ts[d][c] = W[(size_t)(dt * 64 + d) * Ec + c];
        }
        __syncthreads();
        #pragma unroll
        for (int r0 = 0; r0 < 64; r0 += 4) {
            const int e = rr + r0;
            Wt16[(size_t)(proj * 768 + h * 64 + e) * Dc + dt * 64 + c] = (f16)Ts[c][e];
        }
        return;
    }
    bid -= 432;
    if (bid < 144) {           // ---- Wo transpose ----
        const int rt = bid / 12, ct = bid % 12;
        const int c = t & 63, rr = t >> 6;
        #pragma unroll
        for (int r0 = 0; r0 < 64; r0 += 4) {
            const int d = rr + r0;
            Ts[d][c] = Wo[(size_t)(rt * 64 + d) * Dc + ct * 64 + c];
        }
        __syncthreads();
        #pragma unroll
        for (int r0 = 0; r0 < 64; r0 += 4) {
            const int e = rr + r0;
            Wot16[(size_t)(ct * 64 + e) * Dc + rt * 64 + c] = (f16)Ts[c][e];
        }
        return;
    }
    bid -= 144;
    {                          // ---- bias concat ----
        const int g = bid * 256 + t;
        if (g < 3 * 768) {
            const int proj = g / 768, idx = g % 768;
            const float* bb = (proj == 0) ? bq : (proj == 1) ? bk : bv;
            bias_cat[g] = bb[idx];
        }
    }
}

// ---------------------------------------------------------------------------
// Kernel 1: QKV GEMM (fp16 MFMA, global_load_lds staging).
// C[4096,2304] = x16 @ Wt16^T + bias.  Epilogue: q -> [H,B,S,E];
// k -> kswz fragment blobs; v -> vswz fragment blobs.
// ---------------------------------------------------------------------------
__global__ __launch_bounds__(256, 2) void gemm_qkv_kernel(
    const f16* __restrict__ x16, const f16* __restrict__ Wt16,
    const float* __restrict__ bias_cat,
    f16* __restrict__ q16, f16* __restrict__ kswz, f16* __restrict__ vswz)
{
    __shared__ __align__(16) unsigned char smem[34816];
    f16 (*As)[64]  = (f16(*)[64])smem;              // 128 x 64 = 16384 B
    f16 (*Bs)[64]  = (f16(*)[64])(smem + 16384);    // 128 x 64 = 16384 B
    f16 (*Cs)[136] = (f16(*)[136])smem;             // 128 x 136 = 34816 B (post-loop)

    const int t = threadIdx.x;
    const int wave = t >> 6, lane = t & 63;
    const int col = lane & 31, hf = lane >> 5;
    const int wr = wave & 1, wc = wave >> 1;
    const int m0 = blockIdx.x * 128, n0 = blockIdx.y * 128;
    const int lrow = lane >> 3, lseg = lane & 7;    // staging: 8 lanes per row

    floatx16 c00, c01, c10, c11;
    #pragma unroll
    for (int i = 0; i < 16; ++i) { c00[i] = 0.f; c01[i] = 0.f; c10[i] = 0.f; c11[i] = 0.f; }

    for (int k0 = 0; k0 < Dc; k0 += 64) {
        #pragma unroll
        for (int i = 0; i < 4; ++i) {
            const int r = wave * 32 + i * 8;
            __builtin_amdgcn_global_load_lds(
                (glb_cvoid*)(x16 + (size_t)(m0 + r + lrow) * Dc + k0 + lseg * 8),
                (lds_void*)&As[r][0], 16, 0, 0);
            __builtin_amdgcn_global_load_lds(
                (glb_cvoid*)(Wt16 + (size_t)(n0 + r + lrow) * Dc + k0 + lseg * 8),
                (lds_void*)&Bs[r][0], 16, 0, 0);
        }
        __syncthreads();
        #pragma unroll
        for (int ks = 0; ks < 4; ++ks) {
            const half8 a0 = *(const half8*)&As[wr * 64 + col][ks * 16 + hf * 8];
            const half8 a1 = *(const half8*)&As[wr * 64 + 32 + col][ks * 16 + hf * 8];
            const half8 b0 = *(const half8*)&Bs[wc * 64 + col][ks * 16 + hf * 8];
            const half8 b1 = *(const half8*)&Bs[wc * 64 + 32 + col][ks * 16 + hf * 8];
            c00 = __builtin_amdgcn_mfma_f32_32x32x16_f16(a0, b0, c00, 0, 0, 0);
            c01 = __builtin_amdgcn_mfma_f32_32x32x16_f16(a0, b1, c01, 0, 0, 0);
            c10 = __builtin_amdgcn_mfma_f32_32x32x16_f16(a1, b0, c10, 0, 0, 0);
            c11 = __builtin_amdgcn_mfma_f32_32x32x16_f16(a1, b1, c11, 0, 0, 0);
        }
        __syncthreads();
    }

    const float bias0 = bias_cat[n0 + wc * 64 + col];
    const float bias1 = bias_cat[n0 + wc * 64 + 32 + col];
    #pragma unroll
    for (int i = 0; i < 16; ++i) {
        const int r = (i & 3) + 8 * (i >> 2) + 4 * hf;
        Cs[wr * 64 + r][wc * 64 + col]           = (f16)(c00[i] + bias0);
        Cs[wr * 64 + r][wc * 64 + 32 + col]      = (f16)(c01[i] + bias1);
        Cs[wr * 64 + 32 + r][wc * 64 + col]      = (f16)(c10[i] + bias0);
        Cs[wr * 64 + 32 + r][wc * 64 + 32 + col] = (f16)(c11[i] + bias1);
    }
    __syncthreads();

    const int proj = n0 / 768;
    const int h0   = (n0 - proj * 768) >> 6;   // first of two heads in this tile
    const int b    = m0 >> 11;
    const int s_in = m0 & 2047;
    const int kt0  = s_in >> 5;                // first of 4 key-tiles in m-range

    if (proj == 0) {
        const int row = t >> 1, seg = t & 1;
        const int h = h0 + seg;
        f16* gp = q16 + ((size_t)(h * Bc + b) * Sc + s_in + row) * Ec;
        #pragma unroll
        for (int j = 0; j < 8; ++j)
            *(half8*)(gp + j * 8) = *(const half8*)&Cs[row][seg * 64 + j * 8];
    } else if (proj == 1) {
        #pragma unroll
        for (int ch = 0; ch < 8; ++ch) {
            const int id = ch * 256 + t;            // 0..2047
            const int lane_ = id & 63;
            const int ks  = (id >> 6) & 3;
            const int ktp = (id >> 8) & 3;
            const int seg = (id >> 10) & 1;
            const int colp = lane_ & 31, hfp = lane_ >> 5;
            const int hb = (h0 + seg) * Bc + b;
            const half8 val = *(const half8*)&Cs[ktp * 32 + colp][seg * 64 + ks * 16 + hfp * 8];
            *(half8*)(kswz + ((size_t)((hb * 64 + kt0 + ktp) * 4 + ks) << 9) + lane_ * 8) = val;
        }
    } else {
        #pragma unroll
        for (int ch = 0; ch < 8; ++ch) {
            const int id = ch * 256 + t;
            const int lane_ = id & 63;
            const int ks2 = (id >> 6) & 1;
            const int vh  = (id >> 7) & 1;
            const int ktp = (id >> 8) & 3;
            const int seg = (id >> 10) & 1;
            const int colp = lane_ & 31, hfp = lane_ >> 5;
            const int hb = (h0 + seg) * Bc + b;
            const int e  = vh * 32 + colp;
            half8 val;
            #pragma unroll
            for (int j = 0; j < 8; ++j)
                val[j] = Cs[ktp * 32 + ks2 * 16 + hfp * 8 + j][seg * 64 + e];
            *(half8*)(vswz + ((size_t)(((hb * 64 + kt0 + ktp) * 2 + ks2) * 2 + vh) << 9) + lane_ * 8) = val;
        }
    }
}

// ---------------------------------------------------------------------------
// Kernel 2: fp16 MFMA flash attention, two-pass softmax, swizzled K/V
// (every K/V fragment load = contiguous 1 KB per wave).
// ---------------------------------------------------------------------------
__global__ __launch_bounds__(256, 3) void flash_attn_kernel(
    const f16* __restrict__ q16, const f16* __restrict__ kswz,
    const f16* __restrict__ vswz, const float* __restrict__ mask,
    f16* __restrict__ obuf16)
{
    __shared__ _Float16 Plds[4][32][40];
    __shared__ float Msh[2][2][32];
    __shared__ float Lsh[2][32];
    __shared__ float OLsh[2][64][33];

    const int rb   = blockIdx.x;
    const int b    = blockIdx.y;
    const int h    = blockIdx.z;
    const int hb   = h * Bc + b;
    const int t    = threadIdx.x;
    const int wave = t >> 6;
    const int lane = t & 63;
    const int rg   = wave & 1;   // row group
    const int kh   = wave >> 1;  // key half
    const int col  = lane & 31;
    const int hf   = lane >> 5;
    const int row0 = rb * 64 + rg * 32;

    const f16* qb  = q16  + ((size_t)hb * Sc + row0) * Ec;
    const f16* kbz = kswz + ((size_t)hb << 17);   // hb * 64*4*512
    const f16* vbz = vswz + ((size_t)hb << 17);   // hb * 64*2*2*512

    half8 qfrag[4];
    #pragma unroll
    for (int ks = 0; ks < 4; ++ks)
        qfrag[ks] = *(const half8*)(qb + (size_t)col * Ec + ks * 16 + hf * 8);

    constexpr int NT = (Sc / 2) / 32;   // 32 tiles per key-half

    // ======== PASS 1: row max (mask <= 0 ⇒ exp(s-mrow) <= 1 stays safe) ====
    float vmax[16];
    #pragma unroll
    for (int i = 0; i < 16; ++i) vmax[i] = -3e38f;

    for (int kt = 0; kt < NT; ++kt) {
        const int ktg = kh * NT + kt;
        const f16* kp = kbz + ((size_t)ktg << 11) + lane * 8;
        floatx16 c;
        #pragma unroll
        for (int i = 0; i < 16; ++i) c[i] = 0.f;
        #pragma unroll
        for (int ks = 0; ks < 4; ++ks) {
            const half8 kf = *(const half8*)(kp + (ks << 9));
            c = __builtin_amdgcn_mfma_f32_32x32x16_f16(qfrag[ks], kf, c, 0, 0, 0);
        }
        #pragma unroll
        for (int i = 0; i < 16; ++i) vmax[i] = fmaxf(vmax[i], c[i]);
    }
    #pragma unroll
    for (int i = 0; i < 16; ++i) {
        float v = vmax[i];
        v = fmaxf(v, __shfl_xor(v, 1));
        v = fmaxf(v, __shfl_xor(v, 2));
        v = fmaxf(v, __shfl_xor(v, 4));
        v = fmaxf(v, __shfl_xor(v, 8));
        v = fmaxf(v, __shfl_xor(v, 16));
        vmax[i] = v;
    }
    if (col == 0) {
        #pragma unroll
        for (int i = 0; i < 16; ++i) {
            const int r = (i & 3) + 8 * (i >> 2) + 4 * hf;
            Msh[kh][rg][r] = vmax[i];
        }
    }
    __syncthreads();
    float mrow[16];
    #pragma unroll
    for (int i = 0; i < 16; ++i) {
        const int r = (i & 3) + 8 * (i >> 2) + 4 * hf;
        mrow[i] = fmaxf(vmax[i], Msh[1 - kh][rg][r]);
    }

    // ======== PASS 2: exp + PV, no rescaling ================================
    floatx16 o0, o1;
    float lsum[16];
    #pragma unroll
    for (int i = 0; i < 16; ++i) { o0[i] = 0.f; o1[i] = 0.f; lsum[i] = 0.f; }

    const float* mbase = mask + ((size_t)hb * Sc + row0) * Sc + col;
    const int key_base = kh * (Sc / 2);

    float mbuf[16];
    #pragma unroll
    for (int i = 0; i < 16; ++i) {
        const int r = (i & 3) + 8 * (i >> 2) + 4 * hf;
        mbuf[i] = mbase[(size_t)r * Sc + key_base];
    }

    for (int kt = 0; kt < NT; ++kt) {
        const int ktg  = kh * NT + kt;
        const int key0 = key_base + kt * 32;

        float mcur[16];
        #pragma unroll
        for (int i = 0; i < 16; ++i) mcur[i] = mbuf[i];
        if (kt + 1 < NT) {
            #pragma unroll
            for (int i = 0; i < 16; ++i) {
                const int r = (i & 3) + 8 * (i >> 2) + 4 * hf;
                mbuf[i] = mbase[(size_t)r * Sc + key0 + 32];
            }
        }

        const f16* kp = kbz + ((size_t)ktg << 11) + lane * 8;
        floatx16 c;
        #pragma unroll
        for (int i = 0; i < 16; ++i) c[i] = 0.f;
        #pragma unroll
        for (int ks = 0; ks < 4; ++ks) {
            const half8 kf = *(const half8*)(kp + (ks << 9));
            c = __builtin_amdgcn_mfma_f32_32x32x16_f16(qfrag[ks], kf, c, 0, 0, 0);
        }

        #pragma unroll
        for (int i = 0; i < 16; ++i) {
            const float p = __expf(c[i] + mcur[i] - mrow[i]);   // <= 1: fp16-safe
            lsum[i] += p;
            const int r = (i & 3) + 8 * (i >> 2) + 4 * hf;
            Plds[wave][r][col] = (f16)p;
        }
        asm volatile("s_waitcnt lgkmcnt(0)" ::: "memory");

        const f16* vp = vbz + ((size_t)ktg << 11) + lane * 8;
        #pragma unroll
        for (int ks2 = 0; ks2 < 2; ++ks2) {
            const half8 pf = *(const half8*)(&Plds[wave][col][ks2 * 16 + hf * 8]);
            const half8 v0 = *(const half8*)(vp + ((ks2 * 2 + 0) << 9));
            const half8 v1 = *(const half8*)(vp + ((ks2 * 2 + 1) << 9));
            o0 = __builtin_amdgcn_mfma_f32_32x32x16_f16(pf, v0, o0, 0, 0, 0);
            o1 = __builtin_amdgcn_mfma_f32_32x32x16_f16(pf, v1, o1, 0, 0, 0);
        }
    }

    #pragma unroll
    for (int i = 0; i < 16; ++i) {
        float v = lsum[i];
        v += __shfl_xor(v, 1);
        v += __shfl_xor(v, 2);
        v += __shfl_xor(v, 4);
        v += __shfl_xor(v, 8);
        v += __shfl_xor(v, 16);
        lsum[i] = v;
    }

    if (kh == 1) {
        if (col == 0) {
            #pragma unroll
            for (int i = 0; i < 16; ++i) {
                const int r = (i & 3) + 8 * (i >> 2) + 4 * hf;
                Lsh[rg][r] = lsum[i];
            }
        }
        #pragma unroll
        for (int i = 0; i < 16; ++i) {
            OLsh[rg][lane][i]      = o0[i];
            OLsh[rg][lane][16 + i] = o1[i];
        }
    }
    __syncthreads();
    if (kh == 0) {
        #pragma unroll
        for (int i = 0; i < 16; ++i) {
            const int r = (i & 3) + 8 * (i >> 2) + 4 * hf;
            const float inv = 1.f / (lsum[i] + Lsh[rg][r]);
            const float r0 = (o0[i] + OLsh[rg][lane][i])      * inv;
            const float r1 = (o1[i] + OLsh[rg][lane][16 + i]) * inv;
            const size_t orow = ((size_t)b * Sc + row0 + r) * Dc + h * Ec;
            obuf16[orow + col]      = (f16)r0;
            obuf16[orow + 32 + col] = (f16)r1;
        }
    }
}

// ---------------------------------------------------------------------------
// Kernel 3: output GEMM (fp16 MFMA, global_load_lds staging).
// out[4096,768] = obuf16 @ Wot16^T + bo.  128x64 tiles.
// ---------------------------------------------------------------------------
__global__ __launch_bounds__(256, 2) void gemm_out_kernel(
    const f16* __restrict__ a16, const f16* __restrict__ Wot16,
    const float* __restrict__ bo, float* __restrict__ out)
{
    __shared__ __align__(16) f16 As[128][64];
    __shared__ __align__(16) f16 Bs[64][64];

    const int t = threadIdx.x;
    const int wave = t >> 6, lane = t & 63;
    const int col = lane & 31, hf = lane >> 5;
    const int m0 = blockIdx.x * 128, n0 = blockIdx.y * 64;
    const int lrow = lane >> 3, lseg = lane & 7;

    floatx16 c0, c1;
    #pragma unroll
    for (int i = 0; i < 16; ++i) { c0[i] = 0.f; c1[i] = 0.f; }

    for (int k0 = 0; k0 < Dc; k0 += 64) {
        #pragma unroll
        for (int i = 0; i < 4; ++i) {
            const int r = wave * 32 + i * 8;
            __builtin_amdgcn_global_load_lds(
                (glb_cvoid*)(a16 + (size_t)(m0 + r + lrow) * Dc + k0 + lseg * 8),
                (lds_void*)&As[r][0], 16, 0, 0);
        }
        {
            const int r = wave * 16;
            __builtin_amdgcn_global_load_lds(
                (glb_cvoid*)(Wot16 + (size_t)(n0 + r + lrow) * Dc + k0 + lseg * 8),
                (lds_void*)&Bs[r][0], 16, 0, 0);
            __builtin_amdgcn_global_load_lds(
                (glb_cvoid*)(Wot16 + (size_t)(n0 + r + 8 + lrow) * Dc + k0 + lseg * 8),
                (lds_void*)&Bs[r + 8][0], 16, 0, 0);
        }
        __syncthreads();
        #pragma unroll
        for (int ks = 0; ks < 4; ++ks) {
            const half8 a  = *(const half8*)&As[wave * 32 + col][ks * 16 + hf * 8];
            const half8 b0 = *(const half8*)&Bs[col][ks * 16 + hf * 8];
            const half8 b1 = *(const half8*)&Bs[32 + col][ks * 16 + hf * 8];
            c0 = __builtin_amdgcn_mfma_f32_32x32x16_f16(a, b0, c0, 0, 0, 0);
            c1 = __builtin_amdgcn_mfma_f32_32x32x16_f16(a, b1, c1, 0, 0, 0);
        }
        __syncthreads();
    }

    const float bo0 = bo[n0 + col], bo1 = bo[n0 + 32 + col];
    #pragma unroll
    for (int i = 0; i < 16; ++i) {
        const int r = (i & 3) + 8 * (i >> 2) + 4 * hf;
        const size_t ro = (size_t)(m0 + wave * 32 + r) * Dc + n0;
        out[ro + col]      = c0[i] + bo0;
        out[ro + 32 + col] = c1[i] + bo1;
    }
}

// ---------------------------------------------------------------------------
extern "C" void kernel_launch(void* const* d_in, const int* in_sizes, int n_in,
                              void* d_out, int out_size, void* d_ws, size_t ws_size,
                              hipStream_t stream)
{
    const float* x    = (const float*)d_in[0];
    const float* mask = (const float*)d_in[1];
    const float* Wq   = (const float*)d_in[2];
    const float* bq   = (const float*)d_in[3];
    const float* Wk   = (const float*)d_in[4];
    const float* bk   = (const float*)d_in[5];
    const float* Wv   = (const float*)d_in[6];
    const float* bv   = (const float*)d_in[7];
    const float* Wo   = (const float*)d_in[8];
    const float* bo   = (const float*)d_in[9];
    float* out = (float*)d_out;

    constexpr size_t NQ = (size_t)Hc * Bc * Sc * Ec;  // 3,145,728
    f16* x16    = (f16*)d_ws;                      // 4096*768
    f16* Wt16   = x16 + (size_t)BSc * Dc;          // 2304*768
    f16* Wot16  = Wt16 + (size_t)3 * Dc * Dc;      // 768*768
    f16* q16    = Wot16 + (size_t)Dc * Dc;
    f16* kswz   = q16 + NQ;
    f16* vswz   = kswz + NQ;
    f16* obuf16 = vswz + NQ;                       // 4096*768
    float* bias_cat = (float*)(obuf16 + NQ);       // 2304 floats

    prep_kernel<<<2121, 256, 0, stream>>>(x, Wq, Wk, Wv, bq, bk, bv, Wo,
                                          x16, Wt16, Wot16, bias_cat);

    gemm_qkv_kernel<<<dim3(BSc / 128, 2304 / 128), 256, 0, stream>>>(
        x16, Wt16, bias_cat, q16, kswz, vswz);

    flash_attn_kernel<<<dim3(Sc / 64, Bc, Hc), 256, 0, stream>>>(
        q16, kswz, vswz, mask, obuf16);

    gemm_out_kernel<<<dim3(BSc / 128, Dc / 64), 256, 0, stream>>>(
        obuf16, Wot16, bo, out);
}